// Round 13
// baseline (461.118 us; speedup 1.0000x reference)
//
#include <hip/hip_runtime.h>

#define TT  1024
#define DIN 8

// sigma(x) = 1 / (1 + exp2(-x*log2e))
__device__ __forceinline__ float fsig(float x) {
    float e = __builtin_amdgcn_exp2f(-1.4426950408889634f * x);
    return __builtin_amdgcn_rcpf(1.0f + e);
}
// tanh(x) = 2*sigma(2x) - 1
__device__ __forceinline__ float ftanh_(float x) {
    float e = __builtin_amdgcn_exp2f(-2.8853900817779268f * x);
    return 2.0f * __builtin_amdgcn_rcpf(1.0f + e) - 1.0f;
}
// DPP lane permute, compile-time ctrl.
// 0x1B = quad_perm(3,2,1,0): XOR-3.  0xB1 = quad_perm(1,0,3,2): XOR-1.
// 0x118 = row_shr:8, 0x114 = row_shr:4, 0x104 = row_shl:4 (16-lane DPP rows).
template<int CTRL>
__device__ __forceinline__ float dppf(float v) {
    return __uint_as_float((unsigned)__builtin_amdgcn_update_dpp(
        0, (int)__float_as_uint(v), CTRL, 0xF, 0xF, true));
}
// 2-step XOR reduce over a quad (low-2 lane bits): every quad lane gets the sum.
#define RED4(a)  { a += dppf<0x1B>(a); a += dppf<0xB1>(a); }

// lgkm-only barrier: ds_writes visible + ds_reads of the old parity slot
// complete. Global stores (h2 scratch) and x prefetches stay in flight.
__device__ __forceinline__ void bar_lgkm() {
    asm volatile("s_waitcnt lgkmcnt(0)\n\ts_barrier" ::: "memory");
}

// ============================ kernel 1: recurrence ============================
// 16 waves / batch element (block = 1024): waves 0-7 = layer 1, waves 8-15 =
// layer 2; each wave owns 4 hidden units; 16-lane group per unit with lane =
// ul*16 + gate*4 + slice.  4 waves/SIMD (vs 2 in round-11) to interleave the
// ~420 cy/iter of exposed latency identified from R11/R12 counters.
//   L1 lane: 8 h-wts + 2 x-wts; 2 uniform-ish ds_read_b128 + dwordx2 x.
//   L2 lane: 16 wts of the 64-wide [h2|h1] concat; 4 ds_read_b128.
// RED4 (2 DPP) -> full gate dot on all 4 slice lanes; cell update on the
// g-quad via row_shr:8 (i), row_shr:4 (f), row_shl:4 (o); lane (l&15)==8
// publishes. Pipeline at iter t: L1 -> h1(t); L2 -> h2(t-1) (+ scratch store
// to out[b][t-1][0:32]). One lgkm barrier per iteration.
__global__ void __launch_bounds__(1024, 4)
lstm_rec(const float* __restrict__ x,
         const float* __restrict__ Wih1, const float* __restrict__ Whh1,
         const float* __restrict__ bih1, const float* __restrict__ bhh1,
         const float* __restrict__ Wih2, const float* __restrict__ Whh2,
         const float* __restrict__ bih2, const float* __restrict__ bhh2,
         float* __restrict__ out)
{
    const int tid  = threadIdx.x;
    const int wv   = tid >> 6;          // wave 0..15
    const int l    = tid & 63;
    const int sl   = l & 3;             // slice lane within gate-quad
    const int gate = (l >> 2) & 3;      // 0=i 1=f 2=g 3=o
    const int ul   = l >> 4;            // unit-local 0..3
    const int b    = blockIdx.x;
    const bool isL1 = (wv < 8);
    const int  wu   = isL1 ? wv : (wv - 8);
    const int  unit = wu*4 + ul;        // hidden unit 0..31
    const int  R    = gate*32 + unit;   // gate row 0..127
    const bool isg  = (gate == 2);

    __shared__ float hb1[2][32];        // h1 by parity
    __shared__ float hb2[2][32];        // h2 by parity
    if (tid < 64)       ((float*)hb1)[tid]      = 0.f;
    else if (tid < 128) ((float*)hb2)[tid - 64] = 0.f;

    // ---- per-lane weights ----
    float wh[16];                       // L1: 8 used ; L2: 16 used
    float wx0 = 0.f, wx1 = 0.f;         // L1 only
    float bias;
    if (isL1) {
#pragma unroll
        for (int j = 0; j < 8; ++j) wh[j] = Whh1[R*32 + sl*8 + j];
        wx0 = Wih1[R*DIN + sl*2];
        wx1 = Wih1[R*DIN + sl*2 + 1];
        bias = bih1[R] + bhh1[R];
    } else {
        const float* Wb = (sl < 2) ? (Whh2 + R*32 + sl*16)
                                   : (Wih2 + R*32 + (sl-2)*16);
#pragma unroll
        for (int j = 0; j < 16; ++j) wh[j] = Wb[j];
        bias = bih2[R] + bhh2[R];
    }

    float c = 0.f;   // cell; valid on the g-quad lanes, bounded garbage else

    const float* __restrict__ xb = x   + (size_t)b * (TT*DIN);
    float* __restrict__ outb     = out + (size_t)b * (TT*80);

    float2 xcur = make_float2(0.f, 0.f);
    if (isL1) xcur = *reinterpret_cast<const float2*>(xb + sl*2);   // x(0)
    int xoff = DIN + sl*2;              // next x prefetch: x(1)
    const int XMAX = (TT-1)*DIN + sl*2;
    int o2 = 0;                         // running scratch offset: (t-1)*80

    bar_lgkm();   // zero-init visible

#pragma unroll 1
    for (int t = 0; t <= TT; ++t) {
        const int p0  = t & 1;
        const int pm1 = p0 ^ 1;

        if (isL1) {
            if (t < TT) {
                const float* hin = &hb1[pm1][sl*8];
                float4 u0 = reinterpret_cast<const float4*>(hin)[0];
                float4 u1 = reinterpret_cast<const float4*>(hin)[1];
                float a0 = wh[0]*u0.x + wx0*xcur.x;
                float a1 = wh[1]*u0.y + wx1*xcur.y;
                float a2 = wh[2]*u0.z;
                float a3 = wh[3]*u0.w;
                a0 += wh[4]*u1.x;  a1 += wh[5]*u1.y;
                a2 += wh[6]*u1.z;  a3 += wh[7]*u1.w;
                // prefetch next x pair (stays in flight across the barrier)
                xcur = *reinterpret_cast<const float2*>(xb + xoff);
                xoff = (xoff + DIN > XMAX) ? XMAX : (xoff + DIN);

                float acc = (a0 + a1) + (a2 + a3);
                RED4(acc);
                float full = acc + bias;
                float u  = isg ? (full + full) : full;
                float S  = fsig(u);
                float av = isg ? (S + S - 1.0f) : S;    // tanh(g) | sigmoid
                // cell on the g-quad: i <- shr8, f <- shr4, o <- shl4
                float si = dppf<0x118>(av);
                float sf = dppf<0x114>(av);
                float so = dppf<0x104>(av);
                c = sf * c + si * av;                   // av = tanh(g) on g-quad
                float hv = so * ftanh_(c);
                if ((l & 15) == 8) hb1[p0][unit] = hv;  // publish h1(t)
            }
        } else {
            if (t >= 1) {
                const float* hin = (sl < 2) ? &hb2[p0][sl*16]
                                            : &hb1[pm1][(sl-2)*16];
                float4 u0 = reinterpret_cast<const float4*>(hin)[0];
                float4 u1 = reinterpret_cast<const float4*>(hin)[1];
                float4 u2 = reinterpret_cast<const float4*>(hin)[2];
                float4 u3 = reinterpret_cast<const float4*>(hin)[3];
                float a0 = wh[0] *u0.x, a1 = wh[1] *u0.y;
                float a2 = wh[2] *u0.z, a3 = wh[3] *u0.w;
                a0 += wh[4] *u1.x;  a1 += wh[5] *u1.y;
                a2 += wh[6] *u1.z;  a3 += wh[7] *u1.w;
                a0 += wh[8] *u2.x;  a1 += wh[9] *u2.y;
                a2 += wh[10]*u2.z;  a3 += wh[11]*u2.w;
                a0 += wh[12]*u3.x;  a1 += wh[13]*u3.y;
                a2 += wh[14]*u3.z;  a3 += wh[15]*u3.w;

                float acc = (a0 + a1) + (a2 + a3);
                RED4(acc);
                float full = acc + bias;
                float u  = isg ? (full + full) : full;
                float S  = fsig(u);
                float av = isg ? (S + S - 1.0f) : S;
                float si = dppf<0x118>(av);
                float sf = dppf<0x114>(av);
                float so = dppf<0x104>(av);
                c = sf * c + si * av;
                float hv = so * ftanh_(c);
                if ((l & 15) == 8) {
                    hb2[pm1][unit] = hv;                // publish h2(t-1)
                    outb[o2 + unit] = hv;               // scratch for kernel 2
                }
                o2 += 80;
            }
        }

        bar_lgkm();
    }
}

// ============================ kernel 2: out linear ============================
// out[row][0:80] = h2[row] @ Wlin^T + blin, h2 scratch = out[row][0:32].
// Unchanged from round 11 (verified, not in top-5 dispatch cost).
__global__ void __launch_bounds__(256, 4)
out_lin(const float* __restrict__ Wlin, const float* __restrict__ blin,
        float* __restrict__ out, int ntiles)
{
    __shared__ float wl[80][36];
    __shared__ float bl[80];
    __shared__ float ht[16][36];
    const int tid = threadIdx.x;

#pragma unroll 1
    for (int i = tid; i < 640; i += 256) {          // 80 rows x 8 float4
        const int cc = i >> 3, qq = i & 7;
        float4 v = reinterpret_cast<const float4*>(Wlin)[i];
        *reinterpret_cast<float4*>(&wl[cc][qq*4]) = v;
    }
    if (tid < 80) bl[tid] = blin[tid];
    __syncthreads();

    const int row = tid >> 4;   // 0..15
    const int cl  = tid & 15;   // 0..15

#pragma unroll 1
    for (int tile = blockIdx.x; tile < ntiles; tile += gridDim.x) {
        const size_t base = (size_t)tile * 16;
        if (tid < 128) {                            // stage 16 rows of h2
            const int r = tid >> 3, qq = tid & 7;
            float4 v = *reinterpret_cast<const float4*>(out + (base + r)*80 + qq*4);
            *reinterpret_cast<float4*>(&ht[r][qq*4]) = v;
        }
        __syncthreads();

        float hr[32];
#pragma unroll
        for (int j = 0; j < 8; ++j) {
            float4 v = *reinterpret_cast<const float4*>(&ht[row][j*4]);
            hr[4*j]=v.x; hr[4*j+1]=v.y; hr[4*j+2]=v.z; hr[4*j+3]=v.w;
        }
        float res[5];
#pragma unroll
        for (int cj = 0; cj < 5; ++cj) {
            const int cc = cl + 16*cj;
            float a0 = bl[cc], a1 = 0.f, a2 = 0.f, a3 = 0.f;
#pragma unroll
            for (int k = 0; k < 32; k += 4) {
                a0 += wl[cc][k]  *hr[k];   a1 += wl[cc][k+1]*hr[k+1];
                a2 += wl[cc][k+2]*hr[k+2]; a3 += wl[cc][k+3]*hr[k+3];
            }
            res[cj] = (a0 + a1) + (a2 + a3);
        }
        __syncthreads();   // ht reads complete before next tile's staging
#pragma unroll
        for (int cj = 0; cj < 5; ++cj)
            out[(base + row)*80 + cl + 16*cj] = res[cj];
    }
}

extern "C" void kernel_launch(void* const* d_in, const int* in_sizes, int n_in,
                              void* d_out, int out_size, void* d_ws, size_t ws_size,
                              hipStream_t stream) {
    const float* x    = (const float*)d_in[0];
    const float* Wih1 = (const float*)d_in[1];
    const float* Whh1 = (const float*)d_in[2];
    const float* bih1 = (const float*)d_in[3];
    const float* bhh1 = (const float*)d_in[4];
    const float* Wih2 = (const float*)d_in[5];
    const float* Whh2 = (const float*)d_in[6];
    const float* bih2 = (const float*)d_in[7];
    const float* bhh2 = (const float*)d_in[8];
    const float* Wlin = (const float*)d_in[9];
    const float* blin = (const float*)d_in[10];

    const int B = in_sizes[0] / (TT * DIN);   // 256
    const int ntiles = (B * TT) / 16;         // 16384

    hipLaunchKernelGGL(lstm_rec, dim3(B), dim3(1024), 0, stream,
                       x, Wih1, Whh1, bih1, bhh1,
                       Wih2, Whh2, bih2, bhh2,
                       (float*)d_out);
    hipLaunchKernelGGL(out_lin, dim3(2048), dim3(256), 0, stream,
                       Wlin, blin, (float*)d_out, ntiles);
}

// Round 14
// 380.511 us; speedup vs baseline: 1.2118x; 1.2118x over previous
//
#include <hip/hip_runtime.h>

#define TT  1024
#define DIN 8

typedef float f32x2 __attribute__((ext_vector_type(2)));

// sigma(x) = 1 / (1 + exp2(-x*log2e))
__device__ __forceinline__ float fsig(float x) {
    float e = __builtin_amdgcn_exp2f(-1.4426950408889634f * x);
    return __builtin_amdgcn_rcpf(1.0f + e);
}
// tanh(x) = 2*sigma(2x) - 1
__device__ __forceinline__ float ftanh_(float x) {
    float e = __builtin_amdgcn_exp2f(-2.8853900817779268f * x);
    return 2.0f * __builtin_amdgcn_rcpf(1.0f + e) - 1.0f;
}
// DPP lane permute, compile-time ctrl.
// 0xB1 = quad_perm(1,0,3,2): XOR-1. 0x4E = quad_perm(2,3,0,1): XOR-2.
// 0x114 = row_shr:4, 0x112 = row_shr:2, 0x102 = row_shl:2.
template<int CTRL>
__device__ __forceinline__ float dppf(float v) {
    return __uint_as_float((unsigned)__builtin_amdgcn_update_dpp(
        0, (int)__float_as_uint(v), CTRL, 0xF, 0xF, true));
}
// packed 2-wide FMA: lowers to v_pk_fma_f32 (full-rate on CDNA3/4)
__device__ __forceinline__ f32x2 pkfma(f32x2 a, f32x2 b, f32x2 c) {
    return __builtin_elementwise_fma(a, b, c);
}
// lgkm-only barrier: ds_writes visible + ds_reads of the old parity slot
// complete. Global stores (h2 scratch, never read here) and the x prefetch
// stay in flight across it.
__device__ __forceinline__ void bar_lgkm() {
    asm volatile("s_waitcnt lgkmcnt(0)\n\ts_barrier" ::: "memory");
}

// ============================ kernel 1: recurrence ============================
// EXACT round-11 structure (best measured: k1 ~406 us) with ONE change:
// all dot-product FMAs are packed f32x2 -> v_pk_fma_f32, halving the FMA
// instruction count (the dominant VALU term identified from R11-R13 counters).
// 8 waves / batch element. Waves 0-3: layer 1 (2 lanes/gate row, part = half
// of the 32-dot; 4 b128 LDS reads + 10 pk-FMA). Waves 4-7: layer 2 quad-split
// (quad = {g,g^1}x{part}; 4 b128 reads = 16 floats; 2 rows x 8 pk-FMA;
// 3-DPP reduction assembles both rows' full 64-dots). Cell update via DPP
// row_shr4/shr2/shl2. h2(t) fire-and-forget to out[b][t][0:32] scratch for
// kernel 2. One lgkm barrier per timestep-iteration.
__global__ void __launch_bounds__(512, 2)
lstm_rec(const float* __restrict__ x,
         const float* __restrict__ Wih1, const float* __restrict__ Whh1,
         const float* __restrict__ bih1, const float* __restrict__ bhh1,
         const float* __restrict__ Wih2, const float* __restrict__ Whh2,
         const float* __restrict__ bih2, const float* __restrict__ bhh2,
         float* __restrict__ out)
{
    const int tid  = threadIdx.x;
    const int wv   = tid >> 6;         // wave 0..7
    const int l    = tid & 63;
    const int part = l & 1;
    const int g    = (l >> 1) & 3;     // 0=i 1=f 2=g 3=o
    const int ul   = l >> 3;           // unit-local 0..7
    const int b    = blockIdx.x;
    const bool isL1 = (wv < 4);
    const int  wu   = isL1 ? wv : (wv - 4);
    const int  unit = wu*8 + ul;       // hidden unit 0..31
    const bool isg  = (g == 2);

    __shared__ float hb1[2][32];       // h1 by parity
    __shared__ float hb2[2][32];       // h2 by parity
    if (tid < 64)       ((float*)hb1)[tid]      = 0.f;
    else if (tid < 128) ((float*)hb2)[tid - 64] = 0.f;

    // ---- per-lane weights (packed pairs) ----
    f32x2 wgh[8];                // L1: Whh1 half row (16 floats)
    f32x2 wgx[2];                // L1: Wih1 quarter (4 floats)
    f32x2 wa2[8], wb2[8];        // L2: 16 wts of even row, 16 of odd row
    float bias = 0.f;

    if (isL1) {
        const int R = g*32 + unit;
        const float* wsrc = Whh1 + R*32 + part*16;
#pragma unroll
        for (int qq = 0; qq < 8; ++qq)
            wgh[qq] = reinterpret_cast<const f32x2*>(wsrc)[qq];
        const float* xsrc = Wih1 + R*DIN + part*4;
        wgx[0] = reinterpret_cast<const f32x2*>(xsrc)[0];
        wgx[1] = reinterpret_cast<const f32x2*>(xsrc)[1];
        if (!part) bias = bih1[R] + bhh1[R];
    } else {
        const int hs = g & 1;            // which 16-half of the input vector
        const int k2 = g >> 1;           // row-pair selector
        const int Re = (2*k2)*32 + unit;     // even row of pair
        const int Ro = (2*k2+1)*32 + unit;   // odd row of pair
        const int Rw = g*32 + unit;          // own row (bias)
        const float* base = part ? Wih2 : Whh2;  // part1: h1-input, part0: h2
#pragma unroll
        for (int qq = 0; qq < 8; ++qq) {
            wa2[qq] = reinterpret_cast<const f32x2*>(base + Re*32 + hs*16)[qq];
            wb2[qq] = reinterpret_cast<const f32x2*>(base + Ro*32 + hs*16)[qq];
        }
        bias = bih2[Rw] + bhh2[Rw];      // added once, post-reduction (own row)
    }

    float c = 0.f;   // valid on lanes l&7 in {4,5}; bounded garbage elsewhere

    const float* __restrict__ xb = x   + (size_t)b * (TT*DIN);
    float* __restrict__ outb     = out + (size_t)b * (TT*80);

    f32x2 xc0 = {0.f, 0.f}, xc1 = {0.f, 0.f};
    if (isL1) {
        xc0 = reinterpret_cast<const f32x2*>(xb + part*4)[0];   // x(0) half
        xc1 = reinterpret_cast<const f32x2*>(xb + part*4)[1];
    }
    int xoff = DIN;          // float offset of next x prefetch (t=1)
    int o2   = 0;            // running h2-store offset: (t-1)*80

    bar_lgkm();   // zero-init visible

#pragma unroll 1
    for (int t = 0; t <= TT; ++t) {
        const int p0  = t & 1;
        const int pm1 = p0 ^ 1;

        if (isL1) {
            if (t < TT) {
                const float* hin = &hb1[pm1][part << 4];
                f32x2 acc0 = {bias, 0.f}, acc1 = {0.f, 0.f};
#pragma unroll
                for (int qq = 0; qq < 4; ++qq) {
                    float4 v = reinterpret_cast<const float4*>(hin)[qq];
                    f32x2 lo = {v.x, v.y}, hi = {v.z, v.w};
                    acc0 = pkfma(wgh[2*qq],     lo, acc0);
                    acc1 = pkfma(wgh[2*qq + 1], hi, acc1);
                }
                acc0 = pkfma(wgx[0], xc0, acc0);
                acc1 = pkfma(wgx[1], xc1, acc1);
                // prefetch next x half (stays in flight across the barrier)
                xc0 = reinterpret_cast<const f32x2*>(xb + xoff + part*4)[0];
                xc1 = reinterpret_cast<const f32x2*>(xb + xoff + part*4)[1];
                xoff = (xoff + DIN > (TT-1)*DIN) ? (TT-1)*DIN : (xoff + DIN);

                float sum  = (acc0.x + acc0.y) + (acc1.x + acc1.y);
                float full = sum + dppf<0xB1>(sum);      // combine part-halves
                float u  = isg ? (full + full) : full;
                float S  = fsig(u);
                float av = isg ? (S + S - 1.0f) : S;     // tanh(g) | sigmoid
                float itg = dppf<0x114>(av) * av;        // sig(i)*tanh(g)
                float fv  = dppf<0x112>(av);             // sig(f)
                c = fv * c + itg;
                float so  = dppf<0x102>(av);             // sig(o)
                float hv  = so * ftanh_(c);
                if ((l & 7) == 4) hb1[p0][unit] = hv;    // publish h1(t)
            }
        } else {
            if (t >= 1) {
                // quad-split read: 16 floats of (input=part, half=g&1)
                const int hs = g & 1;
                const float* hin = part ? &hb1[pm1][hs << 4] : &hb2[p0][hs << 4];
                f32x2 aE0 = {0.f,0.f}, aE1 = {0.f,0.f};
                f32x2 aO0 = {0.f,0.f}, aO1 = {0.f,0.f};
#pragma unroll
                for (int qq = 0; qq < 4; ++qq) {
                    float4 v = reinterpret_cast<const float4*>(hin)[qq];
                    f32x2 lo = {v.x, v.y}, hi = {v.z, v.w};
                    aE0 = pkfma(wa2[2*qq],     lo, aE0);
                    aE1 = pkfma(wa2[2*qq + 1], hi, aE1);
                    aO0 = pkfma(wb2[2*qq],     lo, aO0);
                    aO1 = pkfma(wb2[2*qq + 1], hi, aO1);
                }
                float accE = (aE0.x + aE0.y) + (aE1.x + aE1.y);
                float accO = (aO0.x + aO0.y) + (aO1.x + aO1.y);
                // step 1 (XOR-1, other input, same hs): combine h1+h2 partials
                accE += dppf<0xB1>(accE);
                accO += dppf<0xB1>(accO);
                // step 2 (XOR-2, other hs & other row-owner): swap complements
                float stage = hs ? accE : accO;   // what partner needs
                float recv  = dppf<0x4E>(stage);  // partner's complement of MY row
                float own   = hs ? accO : accE;
                float full  = own + recv + bias;  // my row's complete 64-dot

                float u  = isg ? (full + full) : full;
                float S  = fsig(u);
                float av = isg ? (S + S - 1.0f) : S;
                float itg = dppf<0x114>(av) * av;
                float fv  = dppf<0x112>(av);
                c = fv * c + itg;
                float so  = dppf<0x102>(av);
                float hv  = so * ftanh_(c);
                if ((l & 7) == 4) {
                    hb2[pm1][unit] = hv;          // publish h2(t-1) for L2
                    outb[o2 + unit] = hv;         // scratch h2 for kernel 2
                }
                o2 += 80;
            }
        }

        bar_lgkm();
    }
}

// ============================ kernel 2: out linear ============================
// out[row][0:80] = h2[row] @ Wlin^T + blin, h2 scratch = out[row][0:32].
// Unchanged from round 11 (verified; not in top-5 dispatch cost).
__global__ void __launch_bounds__(256, 4)
out_lin(const float* __restrict__ Wlin, const float* __restrict__ blin,
        float* __restrict__ out, int ntiles)
{
    __shared__ float wl[80][36];
    __shared__ float bl[80];
    __shared__ float ht[16][36];
    const int tid = threadIdx.x;

#pragma unroll 1
    for (int i = tid; i < 640; i += 256) {          // 80 rows x 8 float4
        const int cc = i >> 3, qq = i & 7;
        float4 v = reinterpret_cast<const float4*>(Wlin)[i];
        *reinterpret_cast<float4*>(&wl[cc][qq*4]) = v;
    }
    if (tid < 80) bl[tid] = blin[tid];
    __syncthreads();

    const int row = tid >> 4;   // 0..15
    const int cl  = tid & 15;   // 0..15

#pragma unroll 1
    for (int tile = blockIdx.x; tile < ntiles; tile += gridDim.x) {
        const size_t base = (size_t)tile * 16;
        if (tid < 128) {                            // stage 16 rows of h2
            const int r = tid >> 3, qq = tid & 7;
            float4 v = *reinterpret_cast<const float4*>(out + (base + r)*80 + qq*4);
            *reinterpret_cast<float4*>(&ht[r][qq*4]) = v;
        }
        __syncthreads();

        float hr[32];
#pragma unroll
        for (int j = 0; j < 8; ++j) {
            float4 v = *reinterpret_cast<const float4*>(&ht[row][j*4]);
            hr[4*j]=v.x; hr[4*j+1]=v.y; hr[4*j+2]=v.z; hr[4*j+3]=v.w;
        }
        float res[5];
#pragma unroll
        for (int cj = 0; cj < 5; ++cj) {
            const int cc = cl + 16*cj;
            float a0 = bl[cc], a1 = 0.f, a2 = 0.f, a3 = 0.f;
#pragma unroll
            for (int k = 0; k < 32; k += 4) {
                a0 += wl[cc][k]  *hr[k];   a1 += wl[cc][k+1]*hr[k+1];
                a2 += wl[cc][k+2]*hr[k+2]; a3 += wl[cc][k+3]*hr[k+3];
            }
            res[cj] = (a0 + a1) + (a2 + a3);
        }
        __syncthreads();   // ht reads complete before next tile's staging
#pragma unroll
        for (int cj = 0; cj < 5; ++cj)
            out[(base + row)*80 + cl + 16*cj] = res[cj];
    }
}

extern "C" void kernel_launch(void* const* d_in, const int* in_sizes, int n_in,
                              void* d_out, int out_size, void* d_ws, size_t ws_size,
                              hipStream_t stream) {
    const float* x    = (const float*)d_in[0];
    const float* Wih1 = (const float*)d_in[1];
    const float* Whh1 = (const float*)d_in[2];
    const float* bih1 = (const float*)d_in[3];
    const float* bhh1 = (const float*)d_in[4];
    const float* Wih2 = (const float*)d_in[5];
    const float* Whh2 = (const float*)d_in[6];
    const float* bih2 = (const float*)d_in[7];
    const float* bhh2 = (const float*)d_in[8];
    const float* Wlin = (const float*)d_in[9];
    const float* blin = (const float*)d_in[10];

    const int B = in_sizes[0] / (TT * DIN);   // 256
    const int ntiles = (B * TT) / 16;         // 16384

    hipLaunchKernelGGL(lstm_rec, dim3(B), dim3(512), 0, stream,
                       x, Wih1, Whh1, bih1, bhh1,
                       Wih2, Whh2, bih2, bhh2,
                       (float*)d_out);
    hipLaunchKernelGGL(out_lin, dim3(2048), dim3(256), 0, stream,
                       Wlin, blin, (float*)d_out, ntiles);
}